// Round 1
// baseline (295.390 us; speedup 1.0000x reference)
//
#include <hip/hip_runtime.h>

// TinyDLRM: out[i] = sigmoid( relu( f @ w1 + b1 ) @ w2 + b2 )
// f = [user_emb(8) | item_emb(8) | cat_emb(8) | dense(2)]  (26 floats)
//
// v2 theory: v1's VGPR_Count=24 proves the compiler sank the table gathers
// into the FMA loops (26 live feature floats cannot fit in 24 regs), so each
// thread serialized ~4 dependent memory round-trips -> latency-bound (all
// counters ~30-70%, nothing saturated). Fix:
//   - 2 samples/thread, ALL 20 loads issued before any FMA (ids -> 12 table
//     gathers -> dense), pinned with an asm memory clobber + sched_barrier(0)
//     so the scheduler cannot re-sink them.
//   - __launch_bounds__(256, 4): 128-VGPR budget so the payload stays in regs.
//   - nontemporal loads/stores for the streaming ids/dense/out so ~100 MB of
//     stream traffic stops evicting table rows from the 4 MiB per-XCD L2s.
// Weights stay as wave-uniform global reads -> SGPRs (s_load + v_fma with
// SGPR operand), as in v1.

#define HIDDEN 16
#define IN_DIM 26

typedef float v4f __attribute__((ext_vector_type(4)));
typedef float v2f __attribute__((ext_vector_type(2)));

__device__ __forceinline__ float mlp_head(
    v4f u0, v4f u1, v4f p0, v4f p1, v4f c0, v4f c1, v2f dd,
    const float* __restrict__ w1, const float* __restrict__ b1,
    const float* __restrict__ w2, const float* __restrict__ b2)
{
    float f[IN_DIM] = {
        u0.x, u0.y, u0.z, u0.w, u1.x, u1.y, u1.z, u1.w,
        p0.x, p0.y, p0.z, p0.w, p1.x, p1.y, p1.z, p1.w,
        c0.x, c0.y, c0.z, c0.w, c1.x, c1.y, c1.z, c1.w,
        dd.x, dd.y
    };

    float h[HIDDEN];
#pragma unroll
    for (int j = 0; j < HIDDEN; ++j) h[j] = b1[j];

#pragma unroll
    for (int k = 0; k < IN_DIM; ++k) {
        float fk = f[k];
#pragma unroll
        for (int j = 0; j < HIDDEN; ++j) {
            h[j] = fmaf(fk, w1[k * HIDDEN + j], h[j]);
        }
    }

    float acc = b2[0];
#pragma unroll
    for (int j = 0; j < HIDDEN; ++j) {
        acc = fmaf(fmaxf(h[j], 0.0f), w2[j], acc);
    }
    return 1.0f / (1.0f + __expf(-acc));
}

__global__ __launch_bounds__(256, 4) void tiny_dlrm_kernel(
    const int*   __restrict__ user_id,
    const int*   __restrict__ item_id,
    const int*   __restrict__ cat_id,
    const float* __restrict__ dense,      // [B,2]
    const float* __restrict__ user_table, // [NU,8]
    const float* __restrict__ item_table, // [NI,8]
    const float* __restrict__ cat_table,  // [NC,8]
    const float* __restrict__ w1,         // [26,16] row-major
    const float* __restrict__ b1,         // [16]
    const float* __restrict__ w2,         // [16]
    const float* __restrict__ b2,         // [1]
    float*       __restrict__ out,        // [B]
    int batch)
{
    const int tid = threadIdx.x;
    const int iA  = blockIdx.x * 512 + tid;
    if (iA >= batch) return;
    const int  iBr  = iA + 256;
    const bool hasB = (iBr < batch);
    const int  iB   = hasB ? iBr : iA;   // clamp to a safe address

    // --- phase 1: issue EVERYTHING ---------------------------------------
    // streaming id loads (nt = evict-first; keep L2 capacity for table rows)
    int uA = __builtin_nontemporal_load(user_id + iA);
    int vA = __builtin_nontemporal_load(item_id + iA);
    int cA = __builtin_nontemporal_load(cat_id  + iA);
    int uB = __builtin_nontemporal_load(user_id + iB);
    int vB = __builtin_nontemporal_load(item_id + iB);
    int cB = __builtin_nontemporal_load(cat_id  + iB);

    // 12 table gathers, back-to-back (one vmcnt wait on ids, then all in flight)
    const v4f* upA = (const v4f*)(user_table + (size_t)uA * 8);
    const v4f* ipA = (const v4f*)(item_table + (size_t)vA * 8);
    const v4f* cpA = (const v4f*)(cat_table  + (size_t)cA * 8);
    const v4f* upB = (const v4f*)(user_table + (size_t)uB * 8);
    const v4f* ipB = (const v4f*)(item_table + (size_t)vB * 8);
    const v4f* cpB = (const v4f*)(cat_table  + (size_t)cB * 8);

    v4f a_u0 = upA[0], a_u1 = upA[1];
    v4f a_i0 = ipA[0], a_i1 = ipA[1];
    v4f a_c0 = cpA[0], a_c1 = cpA[1];
    v4f b_u0 = upB[0], b_u1 = upB[1];
    v4f b_i0 = ipB[0], b_i1 = ipB[1];
    v4f b_c0 = cpB[0], b_c1 = cpB[1];

    v2f ddA = __builtin_nontemporal_load((const v2f*)dense + iA);
    v2f ddB = __builtin_nontemporal_load((const v2f*)dense + iB);

    // pin: no load may sink below this point, no FMA may hoist above it
    asm volatile("" ::: "memory");
    __builtin_amdgcn_sched_barrier(0);

    // --- phase 2: compute ------------------------------------------------
    float oA = mlp_head(a_u0, a_u1, a_i0, a_i1, a_c0, a_c1, ddA, w1, b1, w2, b2);
    __builtin_nontemporal_store(oA, out + iA);

    if (hasB) {
        float oB = mlp_head(b_u0, b_u1, b_i0, b_i1, b_c0, b_c1, ddB, w1, b1, w2, b2);
        __builtin_nontemporal_store(oB, out + iBr);
    }
}

extern "C" void kernel_launch(void* const* d_in, const int* in_sizes, int n_in,
                              void* d_out, int out_size, void* d_ws, size_t ws_size,
                              hipStream_t stream) {
    const int*   user_id    = (const int*)d_in[0];
    const int*   item_id    = (const int*)d_in[1];
    const int*   cat_id     = (const int*)d_in[2];
    const float* dense      = (const float*)d_in[3];
    const float* user_table = (const float*)d_in[4];
    const float* item_table = (const float*)d_in[5];
    const float* cat_table  = (const float*)d_in[6];
    const float* w1         = (const float*)d_in[7];
    const float* b1         = (const float*)d_in[8];
    const float* w2         = (const float*)d_in[9];
    const float* b2         = (const float*)d_in[10];
    float* out = (float*)d_out;

    int batch = in_sizes[0];
    int per_block = 512;                       // 256 threads x 2 samples
    int grid = (batch + per_block - 1) / per_block;
    tiny_dlrm_kernel<<<grid, 256, 0, stream>>>(
        user_id, item_id, cat_id, dense,
        user_table, item_table, cat_table,
        w1, b1, w2, b2, out, batch);
}